// Round 1
// baseline (48025.839 us; speedup 1.0000x reference)
//
#include <hip/hip_runtime.h>
#include <stdint.h>

// LSTM: N=32 batch, T=2048 steps, D=H=512. Persistent kernel.
// 8 groups x 32 WGs; group = blockIdx&7 (same-XCD heuristic under round-robin
// dispatch; correctness relies only on agent-scope atomics). Each WG owns 16
// hidden units (64 gate rows), weights stationary in VGPRs as MFMA A-frags.
// Inputs (x, h) are split hi/lo bf16 for ~f32 accuracy; h exchanged as packed
// (hi<<16|lo) u32 through a ping-pong global buffer with per-WG flags.

#define T_STEPS 2048
#define HD 512
#define NBATCH 32

typedef __attribute__((ext_vector_type(8))) short short8;
typedef __attribute__((ext_vector_type(4))) float f32x4;

static __device__ __forceinline__ uint bf_rne(float f) {
    uint u = __builtin_bit_cast(uint, f);
    return (u + 0x7FFFu + ((u >> 16) & 1u)) >> 16;
}
static __device__ __forceinline__ float bf_f(uint h) {
    return __builtin_bit_cast(float, h << 16);
}
// f32 -> (bf16_hi<<16) | bf16_lo  (hi = rne(f), lo = rne(f - hi))
static __device__ __forceinline__ uint packsplit(float f) {
    uint hi = bf_rne(f);
    uint lo = bf_rne(f - bf_f(hi));
    return (hi << 16) | lo;
}

// Build hi/lo B-fragments (8 bf16 each) from 8 packed u32 (consecutive k).
static __device__ __forceinline__ void buildfrag(const uint* p, short8& bh, short8& bl) {
    uint4 w0 = *(const uint4*)p;
    uint4 w1 = *(const uint4*)(p + 4);
    uint4 hi, lo;
    hi.x = __builtin_amdgcn_perm(w0.y, w0.x, 0x07060302u);
    hi.y = __builtin_amdgcn_perm(w0.w, w0.z, 0x07060302u);
    hi.z = __builtin_amdgcn_perm(w1.y, w1.x, 0x07060302u);
    hi.w = __builtin_amdgcn_perm(w1.w, w1.z, 0x07060302u);
    lo.x = __builtin_amdgcn_perm(w0.y, w0.x, 0x05040100u);
    lo.y = __builtin_amdgcn_perm(w0.w, w0.z, 0x05040100u);
    lo.z = __builtin_amdgcn_perm(w1.y, w1.x, 0x05040100u);
    lo.w = __builtin_amdgcn_perm(w1.w, w1.z, 0x05040100u);
    bh = __builtin_bit_cast(short8, hi);
    bl = __builtin_bit_cast(short8, lo);
}

static __device__ __forceinline__ float sigf(float v) {
    return 1.f / (1.f + __expf(-v));
}
static __device__ __forceinline__ float tanhfast(float v) {
    return 2.f / (1.f + __expf(-2.f * v)) - 1.f;
}

__global__ __launch_bounds__(256, 1) void lstm_pers(
    const float* __restrict__ x, const float* __restrict__ Wih,
    const float* __restrict__ bih, const float* __restrict__ Whh,
    const float* __restrict__ bhh, float* __restrict__ y,
    uint* __restrict__ hbuf, uint* __restrict__ flags)
{
    // wave-private x staging (no barrier: same-wave ds write->read), shared h staging
    __shared__ uint xs[4][4][520];   // [wave][n_local][k] packed hi|lo, pad 520 vs bank conflicts
    __shared__ uint hs[4][520];

    const int b   = blockIdx.x;
    const int g   = b & 7;      // group (4 batch elements)
    const int w   = b >> 3;     // member 0..31 (16-unit slice)
    const int tid = threadIdx.x;
    const int wv  = tid >> 6;   // wave 0..3
    const int l   = tid & 63;
    const int q   = l >> 4;     // quad
    const int m   = l & 15;     // A-row within tile / B-col (batch)

    // ---- stationary weight A-fragments: rows ordered unit*4+gate ----
    // A layout (16x16x32): lane holds A[m=l&15][k=(l>>4)*8 + j]
    const int gateA = m & 3, ulA = m >> 2;
    const int Arow  = gateA * HD + ((w << 4) + (wv << 2) + ulA);
    short8 wf[32];
#pragma unroll
    for (int kt = 0; kt < 32; ++kt) {
        const int k0 = kt * 32 + q * 8;
        const float* src = (k0 < HD) ? (Wih + (size_t)Arow * HD + k0)
                                     : (Whh + (size_t)Arow * HD + (k0 - HD));
        float4 a  = ((const float4*)src)[0];
        float4 c4 = ((const float4*)src)[1];
        uint4 uu;
        uu.x = bf_rne(a.x)  | (bf_rne(a.y)  << 16);
        uu.y = bf_rne(a.z)  | (bf_rne(a.w)  << 16);
        uu.z = bf_rne(c4.x) | (bf_rne(c4.y) << 16);
        uu.w = bf_rne(c4.z) | (bf_rne(c4.w) << 16);
        wf[kt] = __builtin_bit_cast(short8, uu);
    }

    // C layout: lane l holds rows (l>>4)*4 + reg, col = l&15  -> unit = base+q, reg = gate
    const int unitC = (w << 4) + (wv << 2) + q;
    float bias_[4];
#pragma unroll
    for (int i = 0; i < 4; ++i) bias_[i] = bih[i * HD + unitC] + bhh[i * HD + unitC];

    const bool act = (m < 4);                 // only batch cols 0..3 are real
    const size_t ybase = ((size_t)(g * 4 + (m & 3)) * T_STEPS) * HD + unitC;

    const int xn = l >> 4;                    // staged batch row
    const int xk = (l & 15) * 32;             // staged k range (32 elems)

    const f32x4 zero4 = {0.f, 0.f, 0.f, 0.f};
    f32x4 nxh = zero4, nxl = zero4;           // x-projection acc for next step
    float cst = 0.f;

    // Stage x(tt), accumulate W_ih . x into (th_, tl_). Wave-private -> no barrier.
    auto xstage = [&](int tt, f32x4& th_, f32x4& tl_) {
        const float* xp = x + ((size_t)(g * 4 + xn) * T_STEPS + tt) * HD + xk;
#pragma unroll
        for (int j2 = 0; j2 < 8; ++j2) {
            float4 t4 = ((const float4*)xp)[j2];
            uint4 uu;
            uu.x = packsplit(t4.x); uu.y = packsplit(t4.y);
            uu.z = packsplit(t4.z); uu.w = packsplit(t4.w);
            *(uint4*)&xs[wv][xn][xk + 4 * j2] = uu;
        }
#pragma unroll
        for (int kt = 0; kt < 16; ++kt) {
            short8 bh, bl;
            buildfrag(&xs[wv][l & 3][kt * 32 + q * 8], bh, bl);
            th_ = __builtin_amdgcn_mfma_f32_16x16x32_bf16(wf[kt], bh, th_, 0, 0, 0);
            tl_ = __builtin_amdgcn_mfma_f32_16x16x32_bf16(wf[kt], bl, tl_, 0, 0, 0);
        }
    };

    xstage(0, nxh, nxl);   // prologue: v_x(0)

    for (int t = 0; t < T_STEPS; ++t) {
        f32x4 ah = nxh, al = nxl;
        nxh = zero4; nxl = zero4;

        uint h8[8];
        if (t > 0) {
            // wait only for the writer whose slice this thread loads
            uint* fl = flags + (g << 5) + ((tid & 63) >> 1);
            while (__hip_atomic_load(fl, __ATOMIC_ACQUIRE, __HIP_MEMORY_SCOPE_AGENT) < (uint)t)
                __builtin_amdgcn_s_sleep(2);
            uint* hp = hbuf + (size_t)(((t - 1) & 1) * NBATCH + g * 4 + (tid >> 6)) * HD
                       + ((tid & 63) << 3);
#pragma unroll
            for (int j = 0; j < 8; ++j)
                h8[j] = __hip_atomic_load(hp + j, __ATOMIC_RELAXED, __HIP_MEMORY_SCOPE_AGENT);
        }

        // overlap h-load latency with x-projection of t+1
        {
            int tt = t + 1; if (tt > T_STEPS - 1) tt = T_STEPS - 1;
            xstage(tt, nxh, nxl);
        }

        if (t > 0) {
            uint* hd = &hs[tid >> 6][(tid & 63) << 3];
            uint4 u0; u0.x = h8[0]; u0.y = h8[1]; u0.z = h8[2]; u0.w = h8[3];
            uint4 u1; u1.x = h8[4]; u1.y = h8[5]; u1.z = h8[6]; u1.w = h8[7];
            *(uint4*)hd = u0; *(uint4*)(hd + 4) = u1;
            __syncthreads();
#pragma unroll
            for (int kt = 0; kt < 16; ++kt) {
                short8 bh, bl;
                buildfrag(&hs[l & 3][kt * 32 + q * 8], bh, bl);
                ah = __builtin_amdgcn_mfma_f32_16x16x32_bf16(wf[16 + kt], bh, ah, 0, 0, 0);
                al = __builtin_amdgcn_mfma_f32_16x16x32_bf16(wf[16 + kt], bl, al, 0, 0, 0);
            }
        }

        const float v0 = ah.x + al.x + bias_[0];   // i
        const float v1 = ah.y + al.y + bias_[1];   // f
        const float v2 = ah.z + al.z + bias_[2];   // o
        const float v3 = ah.w + al.w + bias_[3];   // g
        const float ig = sigf(v0), fg = sigf(v1), og = sigf(v2), gg = tanhfast(v3);
        cst = fg * cst + ig * gg;
        const float hv = og * tanhfast(cst);

        if (act) {
            y[ybase + (size_t)t * HD] = hv;
            __hip_atomic_store(hbuf + (size_t)((t & 1) * NBATCH + g * 4 + m) * HD + unitC,
                               packsplit(hv), __ATOMIC_RELAXED, __HIP_MEMORY_SCOPE_AGENT);
        }
        __syncthreads();   // all h stores drained (vmcnt) + protects hs reuse
        if (tid == 0)
            __hip_atomic_store(flags + (g << 5) + w, (uint)(t + 1),
                               __ATOMIC_RELEASE, __HIP_MEMORY_SCOPE_AGENT);
    }
}

extern "C" void kernel_launch(void* const* d_in, const int* in_sizes, int n_in,
                              void* d_out, int out_size, void* d_ws, size_t ws_size,
                              hipStream_t stream) {
    (void)in_sizes; (void)n_in; (void)out_size; (void)ws_size;
    const float* x   = (const float*)d_in[0];
    const float* Wih = (const float*)d_in[1];
    const float* bih = (const float*)d_in[2];
    const float* Whh = (const float*)d_in[3];
    const float* bhh = (const float*)d_in[4];
    float* y = (float*)d_out;

    uint* hbuf  = (uint*)d_ws;                                   // 2*32*512*4 = 128 KiB
    uint* flags = (uint*)((char*)d_ws + 2 * NBATCH * HD * 4);    // 8*32*4 = 1 KiB
    hipMemsetAsync(flags, 0, 8 * 32 * 4, stream);
    lstm_pers<<<dim3(256), dim3(256), 0, stream>>>(x, Wih, bih, Whh, bhh, y, hbuf, flags);
}

// Round 2
// 31482.330 us; speedup vs baseline: 1.5255x; 1.5255x over previous
//
#include <hip/hip_runtime.h>
#include <stdint.h>

// LSTM: N=32 batch, T=2048 steps, D=H=512. Persistent kernel, 8 groups x 32 WGs.
// Each WG owns 16 hidden units (64 gate rows), weights stationary in VGPR/AGPR
// MFMA A-fragments. x and h split hi/lo bf16 (two MFMA chains) for ~f32 accuracy.
// Per-step sync: one counter per group; writers fetch_add(release); reader tid0
// polls relaxed + s_sleep, then acquire fence. h exchanged packed (hi|lo) u32 via
// ping-pong global buffer with relaxed agent-scope atomics (cross-XCD safe).
// x-projection of t+1 is computed AFTER publishing h(t) -> off the critical path.

#define T_STEPS 2048
#define HD 512
#define NBATCH 32
#define XSROW 516   // u32 row stride: 516 % 32 == 4 -> conflict-free swizzle

typedef __attribute__((ext_vector_type(8))) short short8;
typedef __attribute__((ext_vector_type(4))) float f32x4;

static __device__ __forceinline__ uint bf_rne(float f) {
    uint u = __builtin_bit_cast(uint, f);
    return (u + 0x7FFFu + ((u >> 16) & 1u)) >> 16;
}
static __device__ __forceinline__ float bf_f(uint h) {
    return __builtin_bit_cast(float, h << 16);
}
// f32 -> (bf16_hi<<16) | bf16_lo  (hi = rne(f), lo = rne(f - hi))
static __device__ __forceinline__ uint packsplit(float f) {
    uint hi = bf_rne(f);
    uint lo = bf_rne(f - bf_f(hi));
    return (hi << 16) | lo;
}

// Build hi/lo B-fragments (8 bf16 each) from 8 packed u32 (consecutive k).
static __device__ __forceinline__ void buildfrag(const uint* p, short8& bh, short8& bl) {
    uint4 w0 = *(const uint4*)p;
    uint4 w1 = *(const uint4*)(p + 4);
    uint4 hi, lo;
    hi.x = __builtin_amdgcn_perm(w0.y, w0.x, 0x07060302u);
    hi.y = __builtin_amdgcn_perm(w0.w, w0.z, 0x07060302u);
    hi.z = __builtin_amdgcn_perm(w1.y, w1.x, 0x07060302u);
    hi.w = __builtin_amdgcn_perm(w1.w, w1.z, 0x07060302u);
    lo.x = __builtin_amdgcn_perm(w0.y, w0.x, 0x05040100u);
    lo.y = __builtin_amdgcn_perm(w0.w, w0.z, 0x05040100u);
    lo.z = __builtin_amdgcn_perm(w1.y, w1.x, 0x05040100u);
    lo.w = __builtin_amdgcn_perm(w1.w, w1.z, 0x05040100u);
    bh = __builtin_bit_cast(short8, hi);
    bl = __builtin_bit_cast(short8, lo);
}

static __device__ __forceinline__ float sigf(float v) {
    return 1.f / (1.f + __expf(-v));
}
static __device__ __forceinline__ float tanhfast(float v) {
    return 2.f / (1.f + __expf(-2.f * v)) - 1.f;
}

__global__ __launch_bounds__(256, 1) void lstm_pers(
    const float* __restrict__ x, const float* __restrict__ Wih,
    const float* __restrict__ bih, const float* __restrict__ Whh,
    const float* __restrict__ bhh, float* __restrict__ y,
    uint* __restrict__ hbuf, uint* __restrict__ cnt)
{
    __shared__ uint xs[4][4 * XSROW];  // per-wave x staging (packed hi|lo)
    __shared__ uint hs[4 * XSROW];     // shared h staging (batch-major)

    const int b   = blockIdx.x;
    const int g   = b & 7;      // group (4 batch elements)
    const int w   = b >> 3;     // member 0..31 (16-unit slice)
    const int tid = threadIdx.x;
    const int wv  = tid >> 6;   // wave 0..3
    const int l   = tid & 63;
    const int q   = l >> 4;     // quad
    const int m   = l & 15;     // A-row within tile / B-col

    // ---- stationary weight A-fragments: rows ordered unit*4+gate ----
    // A layout (16x16x32): lane holds A[m=l&15][k=(l>>4)*8 + j]
    const int gateA = m & 3, ulA = m >> 2;
    const int Arow  = gateA * HD + ((w << 4) + (wv << 2) + ulA);
    short8 wf[32];
#pragma unroll
    for (int kt = 0; kt < 32; ++kt) {
        const int k0 = kt * 32 + q * 8;
        const float* src = (k0 < HD) ? (Wih + (size_t)Arow * HD + k0)
                                     : (Whh + (size_t)Arow * HD + (k0 - HD));
        float4 a  = ((const float4*)src)[0];
        float4 c4 = ((const float4*)src)[1];
        uint4 uu;
        uu.x = bf_rne(a.x)  | (bf_rne(a.y)  << 16);
        uu.y = bf_rne(a.z)  | (bf_rne(a.w)  << 16);
        uu.z = bf_rne(c4.x) | (bf_rne(c4.y) << 16);
        uu.w = bf_rne(c4.z) | (bf_rne(c4.w) << 16);
        wf[kt] = __builtin_bit_cast(short8, uu);
    }

    // C layout: lane l holds rows (l>>4)*4 + reg, col = l&15 -> unit = base+q, reg = gate
    const int unitC = (w << 4) + (wv << 2) + q;
    float bias_[4];
#pragma unroll
    for (int i = 0; i < 4; ++i) bias_[i] = bih[i * HD + unitC] + bhh[i * HD + unitC];

    const bool act = (m < 4);
    const size_t ybase = ((size_t)(g * 4 + (m & 3)) * T_STEPS) * HD + unitC;

    uint* const cg = cnt + (g << 5);           // group counter (own 128B line)

    const f32x4 zero4 = {0.f, 0.f, 0.f, 0.f};
    float cst = 0.f;

    // Stage x(tt) coalesced + conflict-free, accumulate W_ih . x. Wave-private.
    auto xstage = [&](int tt, f32x4& th_, f32x4& tl_) {
        uint* xsw = xs[wv];
#pragma unroll
        for (int n = 0; n < 4; ++n) {
            const float* xp = x + ((size_t)(g * 4 + n) * T_STEPS + tt) * HD;
#pragma unroll
            for (int j2 = 0; j2 < 2; ++j2) {
                const int k0 = j2 * 256 + l * 4;         // lane-contiguous
                float4 t4 = *(const float4*)(xp + k0);
                uint4 uu;
                uu.x = packsplit(t4.x); uu.y = packsplit(t4.y);
                uu.z = packsplit(t4.z); uu.w = packsplit(t4.w);
                *(uint4*)&xsw[n * XSROW + k0] = uu;
            }
        }
#pragma unroll
        for (int kt = 0; kt < 16; ++kt) {
            short8 bh, bl;
            buildfrag(&xsw[(l & 3) * XSROW + kt * 32 + q * 8], bh, bl);
            th_ = __builtin_amdgcn_mfma_f32_16x16x32_bf16(wf[kt], bh, th_, 0, 0, 0);
            tl_ = __builtin_amdgcn_mfma_f32_16x16x32_bf16(wf[kt], bl, tl_, 0, 0, 0);
        }
    };

    f32x4 ah = zero4, al = zero4;
    xstage(0, ah, al);   // prologue: v_x(0)

    for (int t = 0; t < T_STEPS; ++t) {
        if (t > 0) {
            // ---- wait for h(t-1): tid0-only relaxed poll on one address ----
            if (tid == 0) {
                while (__hip_atomic_load(cg, __ATOMIC_RELAXED, __HIP_MEMORY_SCOPE_AGENT)
                       < (uint)(32 * t))
                    __builtin_amdgcn_s_sleep(1);
            }
            __syncthreads();
            __builtin_amdgcn_fence(__ATOMIC_ACQUIRE, "agent");

            // ---- load h(t-1) coalesced, stage to LDS ----
            const uint* hp = hbuf + (size_t)(((t - 1) & 1) * NBATCH + g * 4 + wv) * HD;
#pragma unroll
            for (int j2 = 0; j2 < 2; ++j2) {
                const int k0 = j2 * 256 + l * 4;
                uint4 uu;
                uu.x = __hip_atomic_load(hp + k0 + 0, __ATOMIC_RELAXED, __HIP_MEMORY_SCOPE_AGENT);
                uu.y = __hip_atomic_load(hp + k0 + 1, __ATOMIC_RELAXED, __HIP_MEMORY_SCOPE_AGENT);
                uu.z = __hip_atomic_load(hp + k0 + 2, __ATOMIC_RELAXED, __HIP_MEMORY_SCOPE_AGENT);
                uu.w = __hip_atomic_load(hp + k0 + 3, __ATOMIC_RELAXED, __HIP_MEMORY_SCOPE_AGENT);
                *(uint4*)&hs[wv * XSROW + k0] = uu;
            }
            __syncthreads();
#pragma unroll
            for (int kt = 0; kt < 16; ++kt) {
                short8 bh, bl;
                buildfrag(&hs[(l & 3) * XSROW + kt * 32 + q * 8], bh, bl);
                ah = __builtin_amdgcn_mfma_f32_16x16x32_bf16(wf[16 + kt], bh, ah, 0, 0, 0);
                al = __builtin_amdgcn_mfma_f32_16x16x32_bf16(wf[16 + kt], bl, al, 0, 0, 0);
            }
        }

        const float v0 = ah.x + al.x + bias_[0];   // i
        const float v1 = ah.y + al.y + bias_[1];   // f
        const float v2 = ah.z + al.z + bias_[2];   // o
        const float v3 = ah.w + al.w + bias_[3];   // g
        const float ig = sigf(v0), fg = sigf(v1), og = sigf(v2), gg = tanhfast(v3);
        cst = fg * cst + ig * gg;
        const float hv = og * tanhfast(cst);

        // ---- publish h(t) ASAP (critical path), y-store + xstage after ----
        if (act)
            __hip_atomic_store(hbuf + (size_t)((t & 1) * NBATCH + g * 4 + m) * HD + unitC,
                               packsplit(hv), __ATOMIC_RELAXED, __HIP_MEMORY_SCOPE_AGENT);
        __syncthreads();   // drains all waves' h stores (vmcnt) + protects hs reuse
        if (tid == 0)
            __hip_atomic_fetch_add(cg, 1u, __ATOMIC_RELEASE, __HIP_MEMORY_SCOPE_AGENT);

        if (act) y[ybase + (size_t)t * HD] = hv;

        // x-projection for t+1 — overlaps other WGs' publish latency
        f32x4 nh = zero4, nl = zero4;
        const int tt = (t + 1 < T_STEPS) ? t + 1 : T_STEPS - 1;
        xstage(tt, nh, nl);
        ah = nh; al = nl;
    }
}

extern "C" void kernel_launch(void* const* d_in, const int* in_sizes, int n_in,
                              void* d_out, int out_size, void* d_ws, size_t ws_size,
                              hipStream_t stream) {
    (void)in_sizes; (void)n_in; (void)out_size; (void)ws_size;
    const float* x   = (const float*)d_in[0];
    const float* Wih = (const float*)d_in[1];
    const float* bih = (const float*)d_in[2];
    const float* Whh = (const float*)d_in[3];
    const float* bhh = (const float*)d_in[4];
    float* y = (float*)d_out;

    uint* hbuf = (uint*)d_ws;                                   // 2*32*512*4 = 128 KiB
    uint* cnt  = (uint*)((char*)d_ws + 2 * NBATCH * HD * 4);    // 8 counters, 128B apart
    hipMemsetAsync(cnt, 0, 8 * 32 * 4, stream);
    lstm_pers<<<dim3(256), dim3(256), 0, stream>>>(x, Wih, bih, Whh, bhh, y, hbuf, cnt);
}

// Round 3
// 6249.925 us; speedup vs baseline: 7.6842x; 5.0372x over previous
//
#include <hip/hip_runtime.h>
#include <stdint.h>

// LSTM N=32, T=2048, D=H=512. Persistent kernel, 8 groups x 32 WGs (grid=256=#CUs,
// co-resident). Each WG owns 16 hidden units (64 gate rows); weights stationary in
// VGPR/AGPR MFMA A-fragments, rows ordered unit*4+gate. x and h split hi/lo bf16
// (two MFMA chains) for ~f32 accuracy.
//
// R3: h exchanged via MALL-coherent coalesced vector ops (asm sc0 sc1, bypass
// L1/L2) instead of per-dword agent atomics; no acquire buffer_inv (L1/L2 stay
// warm for x). Release = s_waitcnt vmcnt(0) + relaxed fetch_add. x pre-packed to
// hi|lo bf16 in d_ws (group-local prologue, ws_size-guarded). h-load latency
// overlapped with x-projection MFMA. Publish via LDS by wave0 only -> counter
// bump ASAP. 4 independent MFMA accumulator chains (1 wave/SIMD exposes latency).

#define T_STEPS 2048
#define HD 512
#define NBATCH 32
#define XSROW 516   // u32 row stride: 516 % 32 == 4 -> conflict-free-ish swizzle

typedef __attribute__((ext_vector_type(8))) short short8;
typedef __attribute__((ext_vector_type(4))) float f32x4;
typedef __attribute__((ext_vector_type(4))) uint u32x4;

static __device__ __forceinline__ uint bf_rne(float f) {
    uint u = __builtin_bit_cast(uint, f);
    return (u + 0x7FFFu + ((u >> 16) & 1u)) >> 16;
}
static __device__ __forceinline__ float bf_f(uint h) {
    return __builtin_bit_cast(float, h << 16);
}
// f32 -> (bf16_hi<<16) | bf16_lo
static __device__ __forceinline__ uint packsplit(float f) {
    uint hi = bf_rne(f);
    uint lo = bf_rne(f - bf_f(hi));
    return (hi << 16) | lo;
}

// Build hi/lo B-fragments (8 bf16 each) from 8 packed u32 (consecutive k).
static __device__ __forceinline__ void buildfrag(const uint* p, short8& bh, short8& bl) {
    uint4 w0 = *(const uint4*)p;
    uint4 w1 = *(const uint4*)(p + 4);
    uint4 hi, lo;
    hi.x = __builtin_amdgcn_perm(w0.y, w0.x, 0x07060302u);
    hi.y = __builtin_amdgcn_perm(w0.w, w0.z, 0x07060302u);
    hi.z = __builtin_amdgcn_perm(w1.y, w1.x, 0x07060302u);
    hi.w = __builtin_amdgcn_perm(w1.w, w1.z, 0x07060302u);
    lo.x = __builtin_amdgcn_perm(w0.y, w0.x, 0x05040100u);
    lo.y = __builtin_amdgcn_perm(w0.w, w0.z, 0x05040100u);
    lo.z = __builtin_amdgcn_perm(w1.y, w1.x, 0x05040100u);
    lo.w = __builtin_amdgcn_perm(w1.w, w1.z, 0x05040100u);
    bh = __builtin_bit_cast(short8, hi);
    bl = __builtin_bit_cast(short8, lo);
}

static __device__ __forceinline__ float sigf(float v) { return 1.f / (1.f + __expf(-v)); }
static __device__ __forceinline__ float tanhfast(float v) { return 2.f / (1.f + __expf(-2.f * v)) - 1.f; }

// ---- MALL-coherent (device-scope) coalesced memory ops: sc0 sc1 bypass L1/L2 ----
static __device__ __forceinline__ void st_mall4(uint* p, u32x4 v) {
    asm volatile("global_store_dwordx4 %0, %1, off sc0 sc1" :: "v"(p), "v"(v) : "memory");
}
static __device__ __forceinline__ void st_mall1(uint* p, uint v) {
    asm volatile("global_store_dword %0, %1, off sc0 sc1" :: "v"(p), "v"(v) : "memory");
}
// issue two 16B loads (no wait) — results must not be read until wait_tied2
static __device__ __forceinline__ void ld_mall_issue2(const uint* p0, const uint* p1,
                                                      u32x4& a, u32x4& b) {
    asm volatile("global_load_dwordx4 %0, %2, off sc0 sc1\n\t"
                 "global_load_dwordx4 %1, %3, off sc0 sc1"
                 : "=&v"(a), "=&v"(b) : "v"(p0), "v"(p1) : "memory");
}
static __device__ __forceinline__ void wait_tied2(u32x4& a, u32x4& b) {
    asm volatile("s_waitcnt vmcnt(0)" : "+v"(a), "+v"(b) :: "memory");
}
static __device__ __forceinline__ void waitvm0() {
    asm volatile("s_waitcnt vmcnt(0)" ::: "memory");
}

__global__ __launch_bounds__(256, 1) void lstm_pers(
    const float* __restrict__ x, const float* __restrict__ Wih,
    const float* __restrict__ bih, const float* __restrict__ Whh,
    const float* __restrict__ bhh, float* __restrict__ y,
    uint* __restrict__ hbuf, uint* __restrict__ cnt,
    uint* __restrict__ xpk, int xpre)
{
    __shared__ uint xsh[4 * XSROW];   // shared x staging (4 batch rows, packed)
    __shared__ uint hs[4 * XSROW];    // shared h staging
    __shared__ uint hpub[64];         // publish gather: [batch][unit_local]

    const int b   = blockIdx.x;
    const int g   = b & 7;
    const int w   = b >> 3;
    const int tid = threadIdx.x;
    const int wv  = tid >> 6;
    const int l   = tid & 63;
    const int q   = l >> 4;
    const int m   = l & 15;

    // ---- stationary weight A-fragments: rows ordered unit*4+gate ----
    const int gateA = m & 3, ulA = m >> 2;
    const int Arow  = gateA * HD + ((w << 4) + (wv << 2) + ulA);
    short8 wf[32];
#pragma unroll
    for (int kt = 0; kt < 32; ++kt) {
        const int k0 = kt * 32 + q * 8;
        const float* src = (k0 < HD) ? (Wih + (size_t)Arow * HD + k0)
                                     : (Whh + (size_t)Arow * HD + (k0 - HD));
        float4 a  = ((const float4*)src)[0];
        float4 c4 = ((const float4*)src)[1];
        uint4 uu;
        uu.x = bf_rne(a.x)  | (bf_rne(a.y)  << 16);
        uu.y = bf_rne(a.z)  | (bf_rne(a.w)  << 16);
        uu.z = bf_rne(c4.x) | (bf_rne(c4.y) << 16);
        uu.w = bf_rne(c4.z) | (bf_rne(c4.w) << 16);
        wf[kt] = __builtin_bit_cast(short8, uu);
    }

    const int unitC = (w << 4) + (wv << 2) + q;
    float bias_[4];
#pragma unroll
    for (int i = 0; i < 4; ++i) bias_[i] = bih[i * HD + unitC] + bhh[i * HD + unitC];

    const bool act = (m < 4);
    uint* const cg = cnt + (g << 5);

    // ---- prologue: group-local x -> packed hi|lo bf16 in xpk (if ws fits) ----
    if (xpre) {
        const size_t base = (size_t)(g * 4) * T_STEPS * HD + (size_t)w * 131072u;
#pragma unroll 4
        for (int i = 0; i < 128; ++i) {
            const size_t off = base + (size_t)i * 1024 + (size_t)tid * 4;
            float4 v4 = *(const float4*)(x + off);
            u32x4 u;
            u.x = packsplit(v4.x); u.y = packsplit(v4.y);
            u.z = packsplit(v4.z); u.w = packsplit(v4.w);
            st_mall4(xpk + off, u);
        }
        waitvm0();
        __syncthreads();
        uint* ccg = cnt + 256 + (g << 5);
        if (tid == 0) {
            __hip_atomic_fetch_add(ccg, 1u, __ATOMIC_RELAXED, __HIP_MEMORY_SCOPE_AGENT);
            while (__hip_atomic_load(ccg, __ATOMIC_RELAXED, __HIP_MEMORY_SCOPE_AGENT) < 32u) {}
        }
        __syncthreads();
    }

    // stage one batch row (row wv) of x(tt) into shared xsh
    auto stage_x = [&](int tt) {
        const size_t roff = ((size_t)(g * 4 + wv) * T_STEPS + tt) * HD;
        if (xpre) {
            const uint* xp = xpk + roff;
            u32x4 a = *(const u32x4*)(xp + l * 4);
            u32x4 c = *(const u32x4*)(xp + 256 + l * 4);
            *(u32x4*)&xsh[wv * XSROW + l * 4] = a;
            *(u32x4*)&xsh[wv * XSROW + 256 + l * 4] = c;
        } else {
            const float* xp = x + roff;
#pragma unroll
            for (int j2 = 0; j2 < 2; ++j2) {
                const int k0 = j2 * 256 + l * 4;
                float4 t4 = *(const float4*)(xp + k0);
                u32x4 u;
                u.x = packsplit(t4.x); u.y = packsplit(t4.y);
                u.z = packsplit(t4.z); u.w = packsplit(t4.w);
                *(u32x4*)&xsh[wv * XSROW + k0] = u;
            }
        }
    };

    const f32x4 zero4 = {0.f, 0.f, 0.f, 0.f};
    float cst = 0.f;

    stage_x(0);
    __syncthreads();

    for (int t = 0; t < T_STEPS; ++t) {
        f32x4 a0 = zero4, a1 = zero4, b0 = zero4, b1 = zero4;
        u32x4 ha, hb;

        if (t > 0) {
            if (tid == 0) {
                while (__hip_atomic_load(cg, __ATOMIC_RELAXED, __HIP_MEMORY_SCOPE_AGENT)
                       < 32u * (uint)t) {}
            }
            __syncthreads();
            const uint* hp = hbuf + (size_t)(((t - 1) & 1) * NBATCH + g * 4 + wv) * HD;
            ld_mall_issue2(hp + l * 4, hp + 256 + l * 4, ha, hb);   // issue, no wait
        }

        // x-projection MFMA (reads xsh staged last iter) — hides h-load latency
#pragma unroll
        for (int kt = 0; kt < 16; ++kt) {
            short8 bh, bl;
            buildfrag(&xsh[(l & 3) * XSROW + kt * 32 + q * 8], bh, bl);
            if (kt & 1) {
                a1 = __builtin_amdgcn_mfma_f32_16x16x32_bf16(wf[kt], bh, a1, 0, 0, 0);
                b1 = __builtin_amdgcn_mfma_f32_16x16x32_bf16(wf[kt], bl, b1, 0, 0, 0);
            } else {
                a0 = __builtin_amdgcn_mfma_f32_16x16x32_bf16(wf[kt], bh, a0, 0, 0, 0);
                b0 = __builtin_amdgcn_mfma_f32_16x16x32_bf16(wf[kt], bl, b0, 0, 0, 0);
            }
        }

        if (t > 0) {
            wait_tied2(ha, hb);
            *(u32x4*)&hs[wv * XSROW + l * 4] = ha;
            *(u32x4*)&hs[wv * XSROW + 256 + l * 4] = hb;
            __syncthreads();
#pragma unroll
            for (int kt = 0; kt < 16; ++kt) {
                short8 bh, bl;
                buildfrag(&hs[(l & 3) * XSROW + kt * 32 + q * 8], bh, bl);
                if (kt & 1) {
                    a1 = __builtin_amdgcn_mfma_f32_16x16x32_bf16(wf[16 + kt], bh, a1, 0, 0, 0);
                    b1 = __builtin_amdgcn_mfma_f32_16x16x32_bf16(wf[16 + kt], bl, b1, 0, 0, 0);
                } else {
                    a0 = __builtin_amdgcn_mfma_f32_16x16x32_bf16(wf[16 + kt], bh, a0, 0, 0, 0);
                    b0 = __builtin_amdgcn_mfma_f32_16x16x32_bf16(wf[16 + kt], bl, b0, 0, 0, 0);
                }
            }
        }

        const float v0 = a0.x + a1.x + b0.x + b1.x + bias_[0];   // i
        const float v1 = a0.y + a1.y + b0.y + b1.y + bias_[1];   // f
        const float v2 = a0.z + a1.z + b0.z + b1.z + bias_[2];   // o
        const float v3 = a0.w + a1.w + b0.w + b1.w + bias_[3];   // g
        const float ig = sigf(v0), fg = sigf(v1), og = sigf(v2), gg = tanhfast(v3);
        cst = fg * cst + ig * gg;
        const float hv = og * tanhfast(cst);

        if (act) hpub[m * 16 + ((wv << 2) | q)] = packsplit(hv);
        __syncthreads();   // hpub visible to wave0; xsh reads (x-MFMA) all done

        if (tid < 64) {
            // wave0 publishes the WG's 64 h values (4 batches x 16 units, contiguous)
            const uint p = hpub[tid];
            uint* dst = hbuf + (size_t)((t & 1) * NBATCH + g * 4 + (tid >> 4)) * HD
                        + (w << 4) + (tid & 15);
            st_mall1(dst, p);
            waitvm0();
            if (tid == 0)
                __hip_atomic_fetch_add(cg, 1u, __ATOMIC_RELAXED, __HIP_MEMORY_SCOPE_AGENT);
            const float yv = __builtin_bit_cast(float, p & 0xFFFF0000u)
                           + __builtin_bit_cast(float, p << 16);
            y[((size_t)(g * 4 + (tid >> 4)) * T_STEPS + t) * HD + (w << 4) + (tid & 15)] = yv;
        }

        stage_x(t + 1 < T_STEPS ? t + 1 : T_STEPS - 1);
        // next iteration's poll-__syncthreads protects xsh/hs reuse
    }
}

extern "C" void kernel_launch(void* const* d_in, const int* in_sizes, int n_in,
                              void* d_out, int out_size, void* d_ws, size_t ws_size,
                              hipStream_t stream) {
    (void)in_sizes; (void)n_in; (void)out_size;
    const float* x   = (const float*)d_in[0];
    const float* Wih = (const float*)d_in[1];
    const float* bih = (const float*)d_in[2];
    const float* Whh = (const float*)d_in[3];
    const float* bhh = (const float*)d_in[4];
    float* y = (float*)d_out;

    uint* hbuf = (uint*)d_ws;                              // 128 KiB (2 slots x 32 x 512)
    uint* cnt  = (uint*)((char*)d_ws + 131072);            // 2 KiB counters
    uint* xpk  = (uint*)((char*)d_ws + 131072 + 2048);     // packed x, 128 MiB
    const int xpre = (ws_size >= 134350848ull) ? 1 : 0;
    hipMemsetAsync(cnt, 0, 2048, stream);
    lstm_pers<<<dim3(256), dim3(256), 0, stream>>>(x, Wih, bih, Whh, bhh, y,
                                                   hbuf, cnt, xpk, xpre);
}